// Round 7
// baseline (215.407 us; speedup 1.0000x reference)
//
#include <hip/hip_runtime.h>
#include <stdint.h>

// DEQ: z_{t+1} = tanh(c + z_t @ B_w^T), c = x@A_w^T + A_b + B_b; 5 Picard apps
// (contraction ||B_w||_2 ~= 0.115; T=5 sits at the bf16 comparison floor).
//
// r5 post-mortem: latency-bound at 2 waves/SIMD — cf[8]+acc[8] = 64 unified regs
// (CSV VGPR_Count=108 excludes AGPRs; true alloc ~175). r6 removes cf entirely:
// c is folded into the MFMA K-extension (r1-validated): ext A-frag carries
// A_w cols + bias hi/lo, ext B-frag carries f16(x) + 1.0. Live set ~105 regs
// -> __launch_bounds__(256,4) fits WITHOUT spills (r4 spilled at need ~175/cap 128).
// LDS fragment table = 40 frags x 1 KiB = 40960 B = exactly 4 blocks/CU.
//
// Transposed MFMA: preact^T[s][b] = sum_k Bw_ext[s][k] zext^T[k][b], 16x16x32_f16.
// C-layout (verified): state row = quad*4+reg, batch col = lane&15.
// B-frag rebuilt in-register per app via cross-lane shuffles; bf built per-kt and
// consumed immediately (caps pk+bf joint liveness). No barriers in the loop.

typedef _Float16 half8  __attribute__((ext_vector_type(8)));
typedef __fp16   fp16x2 __attribute__((ext_vector_type(2)));  // cvt_pkrtz native type
typedef float    f32x4  __attribute__((ext_vector_type(4)));
typedef int      int4v  __attribute__((ext_vector_type(4)));

union H2U { fp16x2 h; uint32_t u; };
union BFU { int4v i; half8 h; };

__device__ __forceinline__ float tanh_exact(float v) {
    // tanh(v) = 1 - 2/(e^{2v}+1); v_exp_f32 + v_rcp_f32 (~1 ulp each)
    float e2 = __builtin_amdgcn_exp2f(v * 2.8853900817779268f); // 2*log2(e)
    return 1.0f - 2.0f * __builtin_amdgcn_rcpf(e2 + 1.0f);
}

__device__ __forceinline__ float tanh_poly(float v) {
    // minimax cubic in t=v^2 on |v|<=1.3, abs err <~4e-4; t clamped at 2.1.
    // Intermediate-z errors are damped x0.115 per application downstream.
    float t = v * v;
    t = fminf(t, 2.1f);
    float p = fmaf(-0.017740f, t, 0.103945f);
    p = fmaf(p, t, -0.324360f);
    p = fmaf(p, t, 0.999517f);
    return v * p;
}

__global__ __launch_bounds__(256, 4)
void deq_solve_kernel(const float* __restrict__ xin,
                      const float* __restrict__ A_w,
                      const float* __restrict__ A_b,
                      const float* __restrict__ B_w,
                      const float* __restrict__ B_b,
                      const float* __restrict__ h_w,
                      const float* __restrict__ h_b,
                      float* __restrict__ out)
{
    // Fragment table: frag (mt*5+kt), kt=0..3 from B_w, kt=4 = ext (A_w+bias).
    // Entry = 64 lanes x half8. Total 40 x 1024 B = 40960 B.
    __shared__ __align__(16) _Float16 sb[40 * 64 * 8];

    const int tid  = threadIdx.x;
    const int lane = tid & 63;
    const int wv   = tid >> 6;
    const int quad = lane >> 4;
    const int bcol = lane & 15;

    // ---- one-time: stage B_w fp32 -> f16 LDS in fragment order (kt 0..3) ----
    // A-frag element j of (mt,kt,lane=q*16+b) = B_w[mt*16+b][kt*32+q*8+j]
    for (int i = tid; i < 4096; i += 256) {
        f32x4 v = ((const f32x4*)B_w)[i];           // B_w[row][col4..col4+3]
        int row = i >> 5, col4 = (i & 31) << 2;
        int mt = row >> 4,  b = row & 15;
        int kt = col4 >> 5, q = (col4 >> 3) & 3, j0 = col4 & 7;  // j0 in {0,4}
        H2U h0, h1;
        h0.h = __builtin_amdgcn_cvt_pkrtz(v[0], v[1]);
        h1.h = __builtin_amdgcn_cvt_pkrtz(v[2], v[3]);
        uint32_t* dst = (uint32_t*)(sb + ((mt * 5 + kt) * 64 + q * 16 + b) * 8 + j0);
        dst[0] = h0.u; dst[1] = h1.u;
    }
    // ---- one-time: ext A-frag (kt=4): k=128..135 (quad 0) = A_w cols, bias hi/lo ----
    for (int e = tid; e < 512; e += 256) {
        int mt = e >> 6, ln = e & 63, q = ln >> 4, b = ln & 15;
        half8 v;
        #pragma unroll
        for (int j = 0; j < 8; ++j) v[j] = (_Float16)0.0f;
        if (q == 0) {
            int m = mt * 16 + b;
            f32x4 aw = *(const f32x4*)(A_w + 4 * m);
            float bias = A_b[m] + B_b[m];
            _Float16 bh = (_Float16)bias;
            float blo = bias - (float)bh;          // hi/lo split: bias ~exact in f16 pair
            v[0] = (_Float16)aw[0]; v[1] = (_Float16)aw[1];
            v[2] = (_Float16)aw[2]; v[3] = (_Float16)aw[3];
            v[4] = bh; v[5] = (_Float16)blo;
        }
        *(half8*)(sb + ((mt * 5 + 4) * 64 + ln) * 8) = v;
    }
    __syncthreads();
    const half8* __restrict__ afrag = (const half8*)sb;

    // ---- constant ext B-frag: k=128..131 = f16(x), k=132,133 = 1.0 (quad 0 only) ----
    const int gb = blockIdx.x * 64 + wv * 16 + bcol;
    BFU bext;
    {
        half8 v;
        #pragma unroll
        for (int j = 0; j < 8; ++j) v[j] = (_Float16)0.0f;
        if (quad == 0) {
            f32x4 xv = *(const f32x4*)(xin + 4 * gb);
            v[0] = (_Float16)xv[0]; v[1] = (_Float16)xv[1];
            v[2] = (_Float16)xv[2]; v[3] = (_Float16)xv[3];
            v[4] = (_Float16)1.0f;  v[5] = (_Float16)1.0f;
        }
        bext.h = v;
    }

    int pk0[8], pk1[8];
    const int  s_lo = ((quad & 1) << 5) | bcol;   // source lane for j=0..3
    const int  s_hi = s_lo + 16;                  // source lane for j=4..7
    const bool mlow = (quad < 2);                 // tile select: 2kt vs 2kt+1
    const f32x4 zero4 = {0.f, 0.f, 0.f, 0.f};

    f32x4 acc[8];

#define EPILOGUE(TANH)                                                     \
    _Pragma("unroll")                                                      \
    for (int mt = 0; mt < 8; ++mt) {                                       \
        H2U pa, pb;                                                        \
        pa.h = __builtin_amdgcn_cvt_pkrtz(TANH(acc[mt][0]),                \
                                          TANH(acc[mt][1]));               \
        pb.h = __builtin_amdgcn_cvt_pkrtz(TANH(acc[mt][2]),                \
                                          TANH(acc[mt][3]));               \
        pk0[mt] = (int)pa.u; pk1[mt] = (int)pb.u;                          \
    }

    // Chain: ext tile first (C=0, independent of pk -> issues during shuffles),
    // then kt=0..3 with bf built per-kt and consumed immediately.
#define CHAIN()                                                            \
    _Pragma("unroll")                                                      \
    for (int mt = 0; mt < 8; ++mt)                                         \
        acc[mt] = __builtin_amdgcn_mfma_f32_16x16x32_f16(                  \
            afrag[(mt * 5 + 4) * 64 + lane], bext.h, zero4, 0, 0, 0);      \
    _Pragma("unroll")                                                      \
    for (int kt = 0; kt < 4; ++kt) {                                       \
        int e0 = __shfl(pk0[2*kt],   s_lo), o0 = __shfl(pk0[2*kt+1], s_lo);\
        int e1 = __shfl(pk1[2*kt],   s_lo), o1 = __shfl(pk1[2*kt+1], s_lo);\
        int e2 = __shfl(pk0[2*kt],   s_hi), o2 = __shfl(pk0[2*kt+1], s_hi);\
        int e3 = __shfl(pk1[2*kt],   s_hi), o3 = __shfl(pk1[2*kt+1], s_hi);\
        BFU bfk;                                                           \
        int4v w = { mlow ? e0 : o0, mlow ? e1 : o1,                        \
                    mlow ? e2 : o2, mlow ? e3 : o3 };                      \
        bfk.i = w;                                                         \
        _Pragma("unroll")                                                  \
        for (int mt = 0; mt < 8; ++mt)                                     \
            acc[mt] = __builtin_amdgcn_mfma_f32_16x16x32_f16(              \
                afrag[(mt * 5 + kt) * 64 + lane], bfk.h, acc[mt], 0, 0, 0);\
    }

    // ---- application 1: preact1 = c (ext tile only, z0 = 0) ----
    #pragma unroll
    for (int mt = 0; mt < 8; ++mt)
        acc[mt] = __builtin_amdgcn_mfma_f32_16x16x32_f16(
            afrag[(mt * 5 + 4) * 64 + lane], bext.h, zero4, 0, 0, 0);

    // ---- applications 2..5 ----
    #pragma unroll 1
    for (int it = 0; it < 4; ++it) {
        EPILOGUE(tanh_poly)
        CHAIN()
    }

    // ---- output: y = h_w . tanh(preact5) + h_b (exact tanh, fp32 path) ----
    float partial = 0.f;
    #pragma unroll
    for (int mt = 0; mt < 8; ++mt) {
        f32x4 hw = *(const f32x4*)(h_w + mt * 16 + quad * 4);
        #pragma unroll
        for (int r = 0; r < 4; ++r)
            partial += tanh_exact(acc[mt][r]) * hw[r];
    }
    partial += __shfl_xor(partial, 16);
    partial += __shfl_xor(partial, 32);
    if (quad == 0)
        out[gb] = partial + h_b[0];
}

extern "C" void kernel_launch(void* const* d_in, const int* in_sizes, int n_in,
                              void* d_out, int out_size, void* d_ws, size_t ws_size,
                              hipStream_t stream) {
    const float* x   = (const float*)d_in[0];
    const float* A_w = (const float*)d_in[1];
    const float* A_b = (const float*)d_in[2];
    const float* B_w = (const float*)d_in[3];
    const float* B_b = (const float*)d_in[4];
    const float* h_w = (const float*)d_in[5];
    const float* h_b = (const float*)d_in[6];
    float* outp = (float*)d_out;

    int batch = in_sizes[0] / 4;   // 131072
    int grid  = batch / 64;        // 64 batch rows per block (4 waves x 16)
    deq_solve_kernel<<<grid, 256, 0, stream>>>(x, A_w, A_b, B_w, B_b, h_w, h_b, outp);
}

// Round 8
// 170.166 us; speedup vs baseline: 1.2659x; 1.2659x over previous
//
#include <hip/hip_runtime.h>
#include <stdint.h>

// DEQ: z_{t+1} = tanh(c + z_t @ B_w^T), c = x@A_w^T + A_b + B_b; 5 Picard apps
// (contraction ||B_w||_2 ~= 0.115; T=5 sits at the bf16 comparison floor).
//
// r7 post-mortem: (256,4) = 128-reg unified cap -> spilled (VGPR=64, 600MB scratch
// traffic, 157us). Fully-unrolled CHAIN hoists 4 shuffle groups -> liveness >128.
// r8: (256,3) = 170-reg cap, 3 waves/SIMD (vs r5's 2). Natural liveness of the
// cf-free structure ~130-150 fits under 170 without spills (r5's larger state fit
// at ~175 naturally). LDS 40KiB x 3 blocks/CU = 120KiB < 160KiB, not binding.
//
// Transposed MFMA: preact^T[s][b] = sum_k Bw_ext[s][k] zext^T[k][b], 16x16x32_f16.
// C-layout (verified): state row = quad*4+reg, batch col = lane&15.
// c folded into K-extension (ext A-frag = A_w cols + bias hi/lo; ext B-frag =
// f16(x) + 1.0) — r1-validated bit path. B-frag rebuilt in-register per app via
// cross-lane shuffles; no barriers in the loop (waves fully decoupled).

typedef _Float16 half8  __attribute__((ext_vector_type(8)));
typedef __fp16   fp16x2 __attribute__((ext_vector_type(2)));  // cvt_pkrtz native type
typedef float    f32x4  __attribute__((ext_vector_type(4)));
typedef int      int4v  __attribute__((ext_vector_type(4)));

union H2U { fp16x2 h; uint32_t u; };
union BFU { int4v i; half8 h; };

__device__ __forceinline__ float tanh_exact(float v) {
    // tanh(v) = 1 - 2/(e^{2v}+1); v_exp_f32 + v_rcp_f32 (~1 ulp each)
    float e2 = __builtin_amdgcn_exp2f(v * 2.8853900817779268f); // 2*log2(e)
    return 1.0f - 2.0f * __builtin_amdgcn_rcpf(e2 + 1.0f);
}

__device__ __forceinline__ float tanh_poly(float v) {
    // minimax cubic in t=v^2 on |v|<=1.3, abs err <~4e-4; t clamped at 2.1.
    // Intermediate-z errors are damped x0.115 per application downstream.
    float t = v * v;
    t = fminf(t, 2.1f);
    float p = fmaf(-0.017740f, t, 0.103945f);
    p = fmaf(p, t, -0.324360f);
    p = fmaf(p, t, 0.999517f);
    return v * p;
}

__global__ __launch_bounds__(256, 3)
void deq_solve_kernel(const float* __restrict__ xin,
                      const float* __restrict__ A_w,
                      const float* __restrict__ A_b,
                      const float* __restrict__ B_w,
                      const float* __restrict__ B_b,
                      const float* __restrict__ h_w,
                      const float* __restrict__ h_b,
                      float* __restrict__ out)
{
    // Fragment table: frag (mt*5+kt), kt=0..3 from B_w, kt=4 = ext (A_w+bias).
    // Entry = 64 lanes x half8. Total 40 x 1024 B = 40960 B.
    __shared__ __align__(16) _Float16 sb[40 * 64 * 8];

    const int tid  = threadIdx.x;
    const int lane = tid & 63;
    const int wv   = tid >> 6;
    const int quad = lane >> 4;
    const int bcol = lane & 15;

    // ---- one-time: stage B_w fp32 -> f16 LDS in fragment order (kt 0..3) ----
    // A-frag element j of (mt,kt,lane=q*16+b) = B_w[mt*16+b][kt*32+q*8+j]
    for (int i = tid; i < 4096; i += 256) {
        f32x4 v = ((const f32x4*)B_w)[i];           // B_w[row][col4..col4+3]
        int row = i >> 5, col4 = (i & 31) << 2;
        int mt = row >> 4,  b = row & 15;
        int kt = col4 >> 5, q = (col4 >> 3) & 3, j0 = col4 & 7;  // j0 in {0,4}
        H2U h0, h1;
        h0.h = __builtin_amdgcn_cvt_pkrtz(v[0], v[1]);
        h1.h = __builtin_amdgcn_cvt_pkrtz(v[2], v[3]);
        uint32_t* dst = (uint32_t*)(sb + ((mt * 5 + kt) * 64 + q * 16 + b) * 8 + j0);
        dst[0] = h0.u; dst[1] = h1.u;
    }
    // ---- one-time: ext A-frag (kt=4): k=128..135 (quad 0) = A_w cols, bias hi/lo ----
    for (int e = tid; e < 512; e += 256) {
        int mt = e >> 6, ln = e & 63, q = ln >> 4, b = ln & 15;
        half8 v;
        #pragma unroll
        for (int j = 0; j < 8; ++j) v[j] = (_Float16)0.0f;
        if (q == 0) {
            int m = mt * 16 + b;
            f32x4 aw = *(const f32x4*)(A_w + 4 * m);
            float bias = A_b[m] + B_b[m];
            _Float16 bh = (_Float16)bias;
            float blo = bias - (float)bh;          // hi/lo split: bias ~exact in f16 pair
            v[0] = (_Float16)aw[0]; v[1] = (_Float16)aw[1];
            v[2] = (_Float16)aw[2]; v[3] = (_Float16)aw[3];
            v[4] = bh; v[5] = (_Float16)blo;
        }
        *(half8*)(sb + ((mt * 5 + 4) * 64 + ln) * 8) = v;
    }
    __syncthreads();
    const half8* __restrict__ afrag = (const half8*)sb;

    // ---- constant ext B-frag: k=128..131 = f16(x), k=132,133 = 1.0 (quad 0 only) ----
    const int gb = blockIdx.x * 64 + wv * 16 + bcol;
    BFU bext;
    {
        half8 v;
        #pragma unroll
        for (int j = 0; j < 8; ++j) v[j] = (_Float16)0.0f;
        if (quad == 0) {
            f32x4 xv = *(const f32x4*)(xin + 4 * gb);
            v[0] = (_Float16)xv[0]; v[1] = (_Float16)xv[1];
            v[2] = (_Float16)xv[2]; v[3] = (_Float16)xv[3];
            v[4] = (_Float16)1.0f;  v[5] = (_Float16)1.0f;
        }
        bext.h = v;
    }

    int pk0[8], pk1[8];
    const int  s_lo = ((quad & 1) << 5) | bcol;   // source lane for j=0..3
    const int  s_hi = s_lo + 16;                  // source lane for j=4..7
    const bool mlow = (quad < 2);                 // tile select: 2kt vs 2kt+1
    const f32x4 zero4 = {0.f, 0.f, 0.f, 0.f};

    f32x4 acc[8];

#define EPILOGUE(TANH)                                                     \
    _Pragma("unroll")                                                      \
    for (int mt = 0; mt < 8; ++mt) {                                       \
        H2U pa, pb;                                                        \
        pa.h = __builtin_amdgcn_cvt_pkrtz(TANH(acc[mt][0]),                \
                                          TANH(acc[mt][1]));               \
        pb.h = __builtin_amdgcn_cvt_pkrtz(TANH(acc[mt][2]),                \
                                          TANH(acc[mt][3]));               \
        pk0[mt] = (int)pa.u; pk1[mt] = (int)pb.u;                          \
    }

    // Chain: ext tile first (C=0, independent of pk -> issues during shuffles),
    // then kt=0..3 with bf built per-kt and consumed immediately.
#define CHAIN()                                                            \
    _Pragma("unroll")                                                      \
    for (int mt = 0; mt < 8; ++mt)                                         \
        acc[mt] = __builtin_amdgcn_mfma_f32_16x16x32_f16(                  \
            afrag[(mt * 5 + 4) * 64 + lane], bext.h, zero4, 0, 0, 0);      \
    _Pragma("unroll")                                                      \
    for (int kt = 0; kt < 4; ++kt) {                                       \
        int e0 = __shfl(pk0[2*kt],   s_lo), o0 = __shfl(pk0[2*kt+1], s_lo);\
        int e1 = __shfl(pk1[2*kt],   s_lo), o1 = __shfl(pk1[2*kt+1], s_lo);\
        int e2 = __shfl(pk0[2*kt],   s_hi), o2 = __shfl(pk0[2*kt+1], s_hi);\
        int e3 = __shfl(pk1[2*kt],   s_hi), o3 = __shfl(pk1[2*kt+1], s_hi);\
        BFU bfk;                                                           \
        int4v w = { mlow ? e0 : o0, mlow ? e1 : o1,                        \
                    mlow ? e2 : o2, mlow ? e3 : o3 };                      \
        bfk.i = w;                                                         \
        _Pragma("unroll")                                                  \
        for (int mt = 0; mt < 8; ++mt)                                     \
            acc[mt] = __builtin_amdgcn_mfma_f32_16x16x32_f16(              \
                afrag[(mt * 5 + kt) * 64 + lane], bfk.h, acc[mt], 0, 0, 0);\
    }

    // ---- application 1: preact1 = c (ext tile only, z0 = 0) ----
    #pragma unroll
    for (int mt = 0; mt < 8; ++mt)
        acc[mt] = __builtin_amdgcn_mfma_f32_16x16x32_f16(
            afrag[(mt * 5 + 4) * 64 + lane], bext.h, zero4, 0, 0, 0);

    // ---- applications 2..5 ----
    #pragma unroll 1
    for (int it = 0; it < 4; ++it) {
        EPILOGUE(tanh_poly)
        CHAIN()
    }

    // ---- output: y = h_w . tanh(preact5) + h_b (exact tanh, fp32 path) ----
    float partial = 0.f;
    #pragma unroll
    for (int mt = 0; mt < 8; ++mt) {
        f32x4 hw = *(const f32x4*)(h_w + mt * 16 + quad * 4);
        #pragma unroll
        for (int r = 0; r < 4; ++r)
            partial += tanh_exact(acc[mt][r]) * hw[r];
    }
    partial += __shfl_xor(partial, 16);
    partial += __shfl_xor(partial, 32);
    if (quad == 0)
        out[gb] = partial + h_b[0];
}

extern "C" void kernel_launch(void* const* d_in, const int* in_sizes, int n_in,
                              void* d_out, int out_size, void* d_ws, size_t ws_size,
                              hipStream_t stream) {
    const float* x   = (const float*)d_in[0];
    const float* A_w = (const float*)d_in[1];
    const float* A_b = (const float*)d_in[2];
    const float* B_w = (const float*)d_in[3];
    const float* B_b = (const float*)d_in[4];
    const float* h_w = (const float*)d_in[5];
    const float* h_b = (const float*)d_in[6];
    float* outp = (float*)d_out;

    int batch = in_sizes[0] / 4;   // 131072
    int grid  = batch / 64;        // 64 batch rows per block (4 waves x 16)
    deq_solve_kernel<<<grid, 256, 0, stream>>>(x, A_w, A_b, B_w, B_b, h_w, h_b, outp);
}

// Round 9
// 109.305 us; speedup vs baseline: 1.9707x; 1.5568x over previous
//
#include <hip/hip_runtime.h>
#include <stdint.h>

// DEQ: z_{t+1} = tanh(c + z_t @ B_w^T), c = x@A_w^T + A_b + B_b; 5 Picard apps
// (contraction ||B_w||_2 ~= 0.115; T=5 sits at the bf16 comparison floor).
//
// r8 post-mortem: launch_bounds (256,3)/(256,4) both spill catastrophically (the
// allocator can't fit the natural ~175-reg footprint under 168/128 unified caps).
// And the real r5 bottleneck is the per-CU LDS pipe (shared by all 4 SIMDs):
// 40 ds_read_b128 (A-frags) + 32 bpermutes per wave-app ~= 700 LDS-cyc; x8 waves
// x5 apps matches the 53us. Occupancy adds no LDS throughput -> reduce traffic.
//
// r9: 32 batch rows per wave (two 16-col groups). A-frag reads are batch-
// independent -> amortized 2x. LDS-cyc per batch-row: 44 -> 31. (256,2) known
// no-spill; acc 64 AGPR + pk 32 + bext 8 + temps ~= 155 natural < 256 cap.
//
// Transposed MFMA: preact^T[s][b] = sum_k Bw_ext[s][k] zext^T[k][b], 16x16x32_f16.
// C-layout (verified): state row = quad*4+reg, batch col = lane&15.
// c folded into K-extension (ext A-frag = A_w cols + bias hi/lo; ext B-frag =
// f16(x) + 1.0). B-frags rebuilt in-register per app via cross-lane shuffles;
// no barriers in the loop (waves fully decoupled).

typedef _Float16 half8  __attribute__((ext_vector_type(8)));
typedef __fp16   fp16x2 __attribute__((ext_vector_type(2)));  // cvt_pkrtz native type
typedef float    f32x4  __attribute__((ext_vector_type(4)));
typedef int      int4v  __attribute__((ext_vector_type(4)));

union H2U { fp16x2 h; uint32_t u; };
union BFU { int4v i; half8 h; };

__device__ __forceinline__ float tanh_exact(float v) {
    // tanh(v) = 1 - 2/(e^{2v}+1); v_exp_f32 + v_rcp_f32 (~1 ulp each)
    float e2 = __builtin_amdgcn_exp2f(v * 2.8853900817779268f); // 2*log2(e)
    return 1.0f - 2.0f * __builtin_amdgcn_rcpf(e2 + 1.0f);
}

__device__ __forceinline__ float tanh_poly(float v) {
    // minimax cubic in t=v^2 on |v|<=1.3, abs err <~4e-4; t clamped at 2.1.
    // Intermediate-z errors are damped x0.115 per application downstream.
    float t = v * v;
    t = fminf(t, 2.1f);
    float p = fmaf(-0.017740f, t, 0.103945f);
    p = fmaf(p, t, -0.324360f);
    p = fmaf(p, t, 0.999517f);
    return v * p;
}

__global__ __launch_bounds__(256, 2)
void deq_solve_kernel(const float* __restrict__ xin,
                      const float* __restrict__ A_w,
                      const float* __restrict__ A_b,
                      const float* __restrict__ B_w,
                      const float* __restrict__ B_b,
                      const float* __restrict__ h_w,
                      const float* __restrict__ h_b,
                      float* __restrict__ out)
{
    // Fragment table: frag (mt*5+kt), kt=0..3 from B_w, kt=4 = ext (A_w+bias).
    // Entry = 64 lanes x half8. Total 40 x 1024 B = 40960 B.
    __shared__ __align__(16) _Float16 sb[40 * 64 * 8];

    const int tid  = threadIdx.x;
    const int lane = tid & 63;
    const int wv   = tid >> 6;
    const int quad = lane >> 4;
    const int bcol = lane & 15;

    // ---- one-time: stage B_w fp32 -> f16 LDS in fragment order (kt 0..3) ----
    // A-frag element j of (mt,kt,lane=q*16+b) = B_w[mt*16+b][kt*32+q*8+j]
    for (int i = tid; i < 4096; i += 256) {
        f32x4 v = ((const f32x4*)B_w)[i];           // B_w[row][col4..col4+3]
        int row = i >> 5, col4 = (i & 31) << 2;
        int mt = row >> 4,  b = row & 15;
        int kt = col4 >> 5, q = (col4 >> 3) & 3, j0 = col4 & 7;  // j0 in {0,4}
        H2U h0, h1;
        h0.h = __builtin_amdgcn_cvt_pkrtz(v[0], v[1]);
        h1.h = __builtin_amdgcn_cvt_pkrtz(v[2], v[3]);
        uint32_t* dst = (uint32_t*)(sb + ((mt * 5 + kt) * 64 + q * 16 + b) * 8 + j0);
        dst[0] = h0.u; dst[1] = h1.u;
    }
    // ---- one-time: ext A-frag (kt=4): k=128..135 (quad 0) = A_w cols, bias hi/lo ----
    for (int e = tid; e < 512; e += 256) {
        int mt = e >> 6, ln = e & 63, q = ln >> 4, b = ln & 15;
        half8 v;
        #pragma unroll
        for (int j = 0; j < 8; ++j) v[j] = (_Float16)0.0f;
        if (q == 0) {
            int m = mt * 16 + b;
            f32x4 aw = *(const f32x4*)(A_w + 4 * m);
            float bias = A_b[m] + B_b[m];
            _Float16 bh = (_Float16)bias;
            float blo = bias - (float)bh;          // hi/lo split: bias ~exact in f16 pair
            v[0] = (_Float16)aw[0]; v[1] = (_Float16)aw[1];
            v[2] = (_Float16)aw[2]; v[3] = (_Float16)aw[3];
            v[4] = bh; v[5] = (_Float16)blo;
        }
        *(half8*)(sb + ((mt * 5 + 4) * 64 + ln) * 8) = v;
    }
    __syncthreads();
    const half8* __restrict__ afrag = (const half8*)sb;

    // ---- wave handles 32 batch rows: group g covers gbase + g*16 + bcol ----
    const int gbase = blockIdx.x * 128 + wv * 32;

    // constant ext B-frags: k=128..131 = f16(x), k=132,133 = 1.0 (quad 0 only)
    BFU bext[2];
    #pragma unroll
    for (int g = 0; g < 2; ++g) {
        half8 v;
        #pragma unroll
        for (int j = 0; j < 8; ++j) v[j] = (_Float16)0.0f;
        if (quad == 0) {
            f32x4 xv = *(const f32x4*)(xin + 4 * (gbase + g * 16 + bcol));
            v[0] = (_Float16)xv[0]; v[1] = (_Float16)xv[1];
            v[2] = (_Float16)xv[2]; v[3] = (_Float16)xv[3];
            v[4] = (_Float16)1.0f;  v[5] = (_Float16)1.0f;
        }
        bext[g].h = v;
    }

    int pk0[2][8], pk1[2][8];
    const int  s_lo = ((quad & 1) << 5) | bcol;   // source lane for j=0..3
    const int  s_hi = s_lo + 16;                  // source lane for j=4..7
    const bool mlow = (quad < 2);                 // tile select: 2kt vs 2kt+1
    const f32x4 zero4 = {0.f, 0.f, 0.f, 0.f};

    f32x4 acc[2][8];

    // ---- application 1: preact1 = c (ext tile only, z0 = 0) ----
    #pragma unroll
    for (int mt = 0; mt < 8; ++mt) {
        half8 a = afrag[(mt * 5 + 4) * 64 + lane];      // one read, both groups
        #pragma unroll
        for (int g = 0; g < 2; ++g)
            acc[g][mt] = __builtin_amdgcn_mfma_f32_16x16x32_f16(a, bext[g].h, zero4, 0, 0, 0);
    }

    // ---- applications 2..5 ----
    #pragma unroll 1
    for (int it = 0; it < 4; ++it) {
        // epilogue: tanh + pack to f16 pairs (per group)
        #pragma unroll
        for (int g = 0; g < 2; ++g) {
            #pragma unroll
            for (int mt = 0; mt < 8; ++mt) {
                H2U pa, pb;
                pa.h = __builtin_amdgcn_cvt_pkrtz(tanh_poly(acc[g][mt][0]),
                                                  tanh_poly(acc[g][mt][1]));
                pb.h = __builtin_amdgcn_cvt_pkrtz(tanh_poly(acc[g][mt][2]),
                                                  tanh_poly(acc[g][mt][3]));
                pk0[g][mt] = (int)pa.u; pk1[g][mt] = (int)pb.u;
            }
        }
        // chain: ext tile first (independent of pk -> overlaps shuffles)
        #pragma unroll
        for (int mt = 0; mt < 8; ++mt) {
            half8 a = afrag[(mt * 5 + 4) * 64 + lane];
            #pragma unroll
            for (int g = 0; g < 2; ++g)
                acc[g][mt] = __builtin_amdgcn_mfma_f32_16x16x32_f16(a, bext[g].h, zero4, 0, 0, 0);
        }
        // kt tiles: rebuild B-frag per group via shuffles; A-frag read once per mt
        #pragma unroll
        for (int kt = 0; kt < 4; ++kt) {
            BFU bfk[2];
            #pragma unroll
            for (int g = 0; g < 2; ++g) {
                int e0 = __shfl(pk0[g][2*kt],   s_lo), o0 = __shfl(pk0[g][2*kt+1], s_lo);
                int e1 = __shfl(pk1[g][2*kt],   s_lo), o1 = __shfl(pk1[g][2*kt+1], s_lo);
                int e2 = __shfl(pk0[g][2*kt],   s_hi), o2 = __shfl(pk0[g][2*kt+1], s_hi);
                int e3 = __shfl(pk1[g][2*kt],   s_hi), o3 = __shfl(pk1[g][2*kt+1], s_hi);
                int4v w = { mlow ? e0 : o0, mlow ? e1 : o1,
                            mlow ? e2 : o2, mlow ? e3 : o3 };
                bfk[g].i = w;
            }
            #pragma unroll
            for (int mt = 0; mt < 8; ++mt) {
                half8 a = afrag[(mt * 5 + kt) * 64 + lane];
                #pragma unroll
                for (int g = 0; g < 2; ++g)
                    acc[g][mt] = __builtin_amdgcn_mfma_f32_16x16x32_f16(a, bfk[g].h, acc[g][mt], 0, 0, 0);
            }
        }
    }

    // ---- output: y = h_w . tanh(preact5) + h_b (exact tanh, fp32 path) ----
    float partial[2] = {0.f, 0.f};
    #pragma unroll
    for (int mt = 0; mt < 8; ++mt) {
        f32x4 hw = *(const f32x4*)(h_w + mt * 16 + quad * 4);
        #pragma unroll
        for (int g = 0; g < 2; ++g)
            #pragma unroll
            for (int r = 0; r < 4; ++r)
                partial[g] += tanh_exact(acc[g][mt][r]) * hw[r];
    }
    #pragma unroll
    for (int g = 0; g < 2; ++g) {
        partial[g] += __shfl_xor(partial[g], 16);
        partial[g] += __shfl_xor(partial[g], 32);
    }
    if (quad == 0) {
        float hb = h_b[0];
        out[gbase + bcol]      = partial[0] + hb;
        out[gbase + 16 + bcol] = partial[1] + hb;
    }
}

extern "C" void kernel_launch(void* const* d_in, const int* in_sizes, int n_in,
                              void* d_out, int out_size, void* d_ws, size_t ws_size,
                              hipStream_t stream) {
    const float* x   = (const float*)d_in[0];
    const float* A_w = (const float*)d_in[1];
    const float* A_b = (const float*)d_in[2];
    const float* B_w = (const float*)d_in[3];
    const float* B_b = (const float*)d_in[4];
    const float* h_w = (const float*)d_in[5];
    const float* h_b = (const float*)d_in[6];
    float* outp = (float*)d_out;

    int batch = in_sizes[0] / 4;   // 131072
    int grid  = batch / 128;       // 128 batch rows per block (4 waves x 32)
    deq_solve_kernel<<<grid, 256, 0, stream>>>(x, A_w, A_b, B_w, B_b, h_w, h_b, outp);
}